// Round 11
// baseline (73.209 us; speedup 1.0000x reference)
//
#include <hip/hip_runtime.h>

#define BLK 1024
typedef float v2f __attribute__((ext_vector_type(2)));

__device__ __forceinline__ v2f vbc(float s) { return (v2f){s, s}; }

// minimax atan2, max err ~2e-6 rad; inputs never both zero here
__device__ __forceinline__ float fast_atan2f(float y, float x) {
    float ax = __builtin_fabsf(x), ay = __builtin_fabsf(y);
    float mx = fmaxf(ax, ay), mn = fminf(ax, ay);
    float a  = mn * __builtin_amdgcn_rcpf(mx);
    float s  = a * a;
    float r  = fmaf(s, -0.0117212f,  0.05265332f);
    r = fmaf(s, r, -0.11643287f);
    r = fmaf(s, r,  0.19354346f);
    r = fmaf(s, r, -0.33262347f);
    r = fmaf(s, r,  0.99997726f);
    r *= a;
    if (ay > ax)  r = 1.57079637f - r;
    if (x < 0.0f) r = 3.14159274f - r;
    return copysignf(r, y);
}

// full angle pipeline: returns P (=S+a) , B, via refs; Q = P - B
__device__ __forceinline__ void angle_pipe(v2f v1, v2f v2, float TH, float npl,
                                           float msk, float k_sd, float k4soft,
                                           float k_str, v2f& P, v2f& B) {
    float l2a = fmaf(v1.x, v1.x, v1.y * v1.y);
    float l2b = fmaf(v2.x, v2.x, v2.y * v2.y);
    float cr  = v1.x * v2.y - v1.y * v2.x;
    float dt_ = fmaf(v1.x, v2.x, v1.y * v2.y);
    float theta = fast_atan2f(cr, dt_);
    float cnt = (theta <  TH ? npl        : 0.f)
              + (theta > -TH ? 4.f - npl  : 0.f);
    float K = fmaf(cnt, k_sd, k4soft);
    float m = msk * (K * (theta - TH));
    float ila = __builtin_amdgcn_rsqf(l2a);
    float ilb = __builtin_amdgcn_rsqf(l2b);
    float m1 = m * ila * ila;
    float m2 = m * ilb * ilb;
    float sca = k_str * (1.0f - ila);
    P = vbc(sca) * v1 + vbc(m1) * (v2f){v1.y, -v1.x};   // S + a
    B = vbc(-m2) * (v2f){v2.y, -v2.x};                  // b
}

__global__ __launch_bounds__(BLK)
void equil_kernel(const float* __restrict__ pos0,
                  const float* __restrict__ tip_pos,
                  const float* __restrict__ thetas_ss,
                  const int*   __restrict__ buckle,
                  const float* __restrict__ kstiff_p,
                  const float* __restrict__ ksoft_p,
                  const float* __restrict__ kstretch_p,
                  float* __restrict__ out)
{
    // double-buffered positions; slots 1026,1027 = finite pads
    __shared__ v2f buf0[1028], buf1[1028];
    // per-wave P/Q region: [0..65]=P (64 main + 2 halo), [68..133]=Q
    __shared__ v2f PQ[16][136];

    const int b = blockIdx.x;
    const int t = threadIdx.x;
    const int l = t & 63;
    v2f* PQw = PQ[t >> 6];
    const float k_str  = kstretch_p[0];
    const float k_sd   = kstiff_p[0] - ksoft_p[0];
    const float k4soft = 4.0f * ksoft_p[0];

    // ---- init: thread t = angle t, owns node t+2 ----
    const v2f* p0g = (const v2f*)(pos0 + (size_t)b * 2052);
    v2f myp;
    if (t < 1023) myp = p0g[t + 2];
    else          myp = (v2f){tip_pos[2*b], tip_pos[2*b+1]};
    buf0[t + 2] = myp;  buf1[t + 2] = myp;
    if (t < 2)  { buf0[t] = p0g[t]; buf1[t] = p0g[t]; }   // fixed nodes
    if (t == 2) {
        buf0[1026] = (v2f){1.f, 0.5f};   buf1[1026] = (v2f){1.f, 0.5f};
        buf0[1027] = (v2f){2.f, 0.25f};  buf1[1027] = (v2f){2.f, 0.25f};
    }

    const float TH = thetas_ss[t];
    const int4 bk  = ((const int4*)buckle)[t];
    const float npl = (float)(bk.x + bk.y + bk.z + bk.w);
    // halo-angle constants (angle t+2), clamped; msk2 kills angles >= 1024
    const int   t2c  = (t + 2 < 1024) ? t + 2 : 1023;
    const float TH2  = thetas_ss[t2c];
    const int4  bk2  = ((const int4*)buckle)[t2c];
    const float npl2 = (float)(bk2.x + bk2.y + bk2.z + bk2.w);
    const float msk2 = (t + 2 < 1024) ? 1.f : 0.f;

    v2f vel = vbc(0.f);
    __syncthreads();

    v2f* br = buf0;
    v2f* bw = buf1;
    for (int s = 0; s < 64; ++s) {
        // ---- main angle t: nodes t, t+1 (LDS), t+2 (own reg) ----
        v2f pa = br[t], pb = br[t + 1];
        v2f P, Bv;
        angle_pipe(pb - pa, myp - pb, TH, npl, 1.f, k_sd, k4soft, k_str, P, Bv);
        PQw[l]      = P;
        PQw[68 + l] = P - Bv;

        // ---- halo: lanes 62,63 also compute angle t+2 (nodes t+2..t+4) ----
        if (l >= 62) {
            v2f hb = br[t + 3], hc = br[t + 4];
            v2f Ph, Bh;
            angle_pipe(hb - myp, hc - hb, TH2, npl2, msk2, k_sd, k4soft, k_str, Ph, Bh);
            PQw[l + 2]      = Ph;         // slots 64,65
            PQw[68 + l + 2] = Ph - Bh;
        }

        // ---- phase C (wave-local): f = P[t+2] - Q[t+1] - B[t] ----
        v2f Pn = PQw[l + 2];
        v2f Qm = PQw[68 + l + 1];
        if (t < 1023) {
            v2f f = (Pn - Qm) - Bv;
            vel = vel + vbc(0.001f) * (f - vbc(2.0f) * vel);
            myp = myp + vbc(0.001f) * vel;
        }
        bw[t + 2] = myp;
        __syncthreads();
        v2f* tmp = br; br = bw; bw = tmp;
    }

    // ---- epilogue ----
    v2f* o = (v2f*)(out + (size_t)b * 2052);
    o[t + 2] = myp;                 // t=1023 writes node 1025 = tip
    if (t < 2) o[t] = buf0[t];      // fixed nodes 0,1
}

extern "C" void kernel_launch(void* const* d_in, const int* in_sizes, int n_in,
                              void* d_out, int out_size, void* d_ws, size_t ws_size,
                              hipStream_t stream) {
    const float* pos0   = (const float*)d_in[0];
    const float* tip    = (const float*)d_in[1];
    const float* thetas = (const float*)d_in[2];
    const int*   buckle = (const int*)  d_in[3];
    const float* ks     = (const float*)d_in[4];
    const float* ko     = (const float*)d_in[5];
    const float* kr     = (const float*)d_in[6];
    float* out = (float*)d_out;
    hipLaunchKernelGGL(equil_kernel, dim3(256), dim3(BLK), 0, stream,
                       pos0, tip, thetas, buckle, ks, ko, kr, out);
}

// Round 12
// 48.978 us; speedup vs baseline: 1.4947x; 1.4947x over previous
//
#include <hip/hip_runtime.h>

#define NN 1026   // nodes
#define NA 1024   // angles
#define BLK 1024
typedef float v2f __attribute__((ext_vector_type(2)));

__device__ __forceinline__ v2f vbc(float s) { return (v2f){s, s}; }

// minimax atan2, max err ~1e-5 rad; inputs never both zero here
__device__ __forceinline__ float fast_atan2f(float y, float x) {
    float ax = __builtin_fabsf(x), ay = __builtin_fabsf(y);
    float mx = fmaxf(ax, ay), mn = fminf(ax, ay);
    float a  = mn * __builtin_amdgcn_rcpf(mx);
    float s  = a * a;
    float r  = fmaf(s,  0.03089885f, -0.08705134f);
    r = fmaf(s, r,  0.18014812f);
    r = fmaf(s, r, -0.33069677f);
    r = fmaf(s, r,  0.99999295f);
    r *= a;
    if (ay > ax)  r = 1.57079637f - r;
    if (x < 0.0f) r = 3.14159274f - r;
    return copysignf(r, y);
}

__global__ __launch_bounds__(BLK)
void equil_kernel(const float* __restrict__ pos0,
                  const float* __restrict__ tip_pos,
                  const float* __restrict__ thetas_ss,
                  const int*   __restrict__ buckle,
                  const float* __restrict__ kstiff_p,
                  const float* __restrict__ ksoft_p,
                  const float* __restrict__ kstretch_p,
                  float* __restrict__ out)
{
    __shared__ v2f pos[NN];      // node positions
    __shared__ v2f Ps[NA + 1];   // P_j = S_j + a_j ; slot 1024 = S_1024
    __shared__ v2f Qs[NA];       // Q_j = P_j - B_j

    const int b = blockIdx.x;
    const int t = threadIdx.x;
    const float k_str  = kstretch_p[0];
    const float k_sd   = kstiff_p[0] - ksoft_p[0];
    const float k4soft = 4.0f * ksoft_p[0];

    // ---- init: thread t computes angle t, owns node t+2 (free for t<=1022) ----
    const v2f* p0g = (const v2f*)(pos0 + (size_t)b * 2052);
    v2f myp;
    if (t < 1023) myp = p0g[t + 2];
    else          myp = (v2f){tip_pos[2*b], tip_pos[2*b+1]};
    pos[t + 2] = myp;
    if (t < 2) pos[t] = p0g[t];      // fixed nodes 0,1

    const float TH = thetas_ss[t];
    const int4 bk  = ((const int4*)buckle)[t];
    const float npl = (float)(bk.x + bk.y + bk.z + bk.w);   // #(pm==+1)
    v2f vel = vbc(0.f);
    __syncthreads();

    for (int s = 0; s < 64; ++s) {
        // ---- phase AB: angle t from pos[t], pos[t+1] (adjacent reads), own myp ----
        v2f pa = pos[t], pb = pos[t + 1];
        v2f v1 = pb - pa;
        v2f v2 = myp - pb;
        float l2a = fmaf(v1.x, v1.x, v1.y * v1.y);
        float l2b = fmaf(v2.x, v2.x, v2.y * v2.y);
        float cr  = v1.x * v2.y - v1.y * v2.x;
        float dt_ = fmaf(v1.x, v2.x, v1.y * v2.y);
        float theta = fast_atan2f(cr, dt_);
        float cnt = (theta <  TH ? npl        : 0.f)
                  + (theta > -TH ? 4.f - npl  : 0.f);
        float K = fmaf(cnt, k_sd, k4soft);
        float m = K * (theta - TH);
        float ila = __builtin_amdgcn_rsqf(l2a);
        float ilb = __builtin_amdgcn_rsqf(l2b);
        float m1 = m * ila * ila;                  // m / l2a
        float m2 = m * ilb * ilb;                  // m / l2b
        v2f rot1 = (v2f){ v1.y, -v1.x};
        v2f rot2 = (v2f){ v2.y, -v2.x};
        v2f Bv = vbc(-m2) * rot2;                  // b_t (register only)
        float sca = k_str * (1.0f - ila);
        v2f P  = vbc(sca) * v1 + vbc(m1) * rot1;   // S_t + a_t  (pk_fma)
        v2f Q  = P - Bv;
        Ps[t] = P;
        Qs[t] = Q;
        if (t == NA - 1) {   // slot 1024: S_1024 (stretch-only edge)
            float scb = k_str * (1.0f - ilb);
            Ps[NA] = vbc(scb) * v2;
        }
        __syncthreads();

        // ---- phase C: f(node t+2) = P[t+2] - Q[t+1] - B[t] ----
        if (t < 1023) {
            v2f Pn = Ps[t + 2];
            v2f Qm = Qs[t + 1];
            v2f f  = (Pn - Qm) - Bv;
            vel = vel + vbc(0.001f) * (f - vbc(2.0f) * vel);   // reference form
            myp = myp + vbc(0.001f) * vel;
            pos[t + 2] = myp;
        }
        __syncthreads();
    }

    // ---- epilogue ----
    v2f* o = (v2f*)(out + (size_t)b * 2052);
    o[t + 2] = myp;            // t=1023 writes node 1025 = tip
    if (t < 2) o[t] = pos[t];
}

extern "C" void kernel_launch(void* const* d_in, const int* in_sizes, int n_in,
                              void* d_out, int out_size, void* d_ws, size_t ws_size,
                              hipStream_t stream) {
    const float* pos0   = (const float*)d_in[0];
    const float* tip    = (const float*)d_in[1];
    const float* thetas = (const float*)d_in[2];
    const int*   buckle = (const int*)  d_in[3];
    const float* ks     = (const float*)d_in[4];
    const float* ko     = (const float*)d_in[5];
    const float* kr     = (const float*)d_in[6];
    float* out = (float*)d_out;
    hipLaunchKernelGGL(equil_kernel, dim3(256), dim3(BLK), 0, stream,
                       pos0, tip, thetas, buckle, ks, ko, kr, out);
}

// Round 13
// 45.120 us; speedup vs baseline: 1.6225x; 1.0855x over previous
//
#include <hip/hip_runtime.h>

#define NN 1026   // nodes
#define NA 1024   // angles
#define BLK 1024

// minimax atan2, max err ~2e-6 rad; inputs never both zero here
__device__ __forceinline__ float fast_atan2f(float y, float x) {
    float ax = __builtin_fabsf(x), ay = __builtin_fabsf(y);
    float mx = fmaxf(ax, ay), mn = fminf(ax, ay);
    float a  = mn * __builtin_amdgcn_rcpf(mx);
    float s  = a * a;
    float r  = fmaf(s, -0.0117212f,  0.05265332f);
    r = fmaf(s, r, -0.11643287f);
    r = fmaf(s, r,  0.19354346f);
    r = fmaf(s, r, -0.33262347f);
    r = fmaf(s, r,  0.99997726f);
    r *= a;
    if (ay > ax)  r = 1.57079637f - r;
    if (x < 0.0f) r = 3.14159274f - r;
    return copysignf(r, y);
}

__global__ __launch_bounds__(BLK)
void equil_kernel(const float* __restrict__ pos0,
                  const float* __restrict__ tip_pos,
                  const float* __restrict__ thetas_ss,
                  const int*   __restrict__ buckle,
                  const float* __restrict__ kstiff_p,
                  const float* __restrict__ ksoft_p,
                  const float* __restrict__ kstretch_p,
                  float* __restrict__ out)
{
    // double-buffered state
    __shared__ float2 posB0[NN],    posB1[NN];
    __shared__ float2 PsB0[NA + 1], PsB1[NA + 1];
    __shared__ float2 QsB0[NA],     QsB1[NA];

    const int b = blockIdx.x;
    const int t = threadIdx.x;
    const int l = t & 63;
    const float k_str  = kstretch_p[0];
    const float k_sd   = kstiff_p[0] - ksoft_p[0];
    const float k4soft = 4.0f * ksoft_p[0];

    // ---- init: thread t computes angle t, owns node t+2 (free for t<=1022) ----
    const float2* p0g = (const float2*)(pos0 + (size_t)b * 2052);
    float2 myp;
    if (t < 1023) myp = p0g[t + 2];
    else          { myp.x = tip_pos[2*b]; myp.y = tip_pos[2*b+1]; }
    posB0[t + 2] = myp;  posB1[t + 2] = myp;
    if (t < 2) { posB0[t] = p0g[t]; posB1[t] = p0g[t]; }   // fixed nodes 0,1

    const float TH = thetas_ss[t];
    const int4 bk  = ((const int4*)buckle)[t];
    const float npl = (float)(bk.x + bk.y + bk.z + bk.w);   // #(pm==+1)
    float2 vel = make_float2(0.f, 0.f);
    __syncthreads();

    // shared AB math (identical arithmetic everywhere)
#define AB_MATH(posR)                                                         \
        float2 pa = posR[t], pb = posR[t + 1];                                \
        float v1x = pb.x - pa.x,  v1y = pb.y - pa.y;                          \
        float v2x = myp.x - pb.x, v2y = myp.y - pb.y;                         \
        float l2a = fmaf(v1x, v1x, v1y * v1y);                                \
        float l2b = fmaf(v2x, v2x, v2y * v2y);                                \
        float cr  = v1x * v2y - v1y * v2x;                                    \
        float dt_ = fmaf(v1x, v2x, v1y * v2y);                                \
        float theta = fast_atan2f(cr, dt_);                                   \
        float cnt = (theta <  TH ? npl        : 0.f)                          \
                  + (theta > -TH ? 4.f - npl  : 0.f);                         \
        float K = fmaf(cnt, k_sd, k4soft);                                    \
        float m = K * (theta - TH);                                           \
        float ila = __builtin_amdgcn_rsqf(l2a);                               \
        float ilb = __builtin_amdgcn_rsqf(l2b);                               \
        float m1 = m * ila * ila;                                             \
        float m2 = m * ilb * ilb;                                             \
        float2 Bv; Bv.x = -m2 * v2y;  Bv.y =  m2 * v2x;                       \
        float sca = k_str * (1.0f - ila);                                     \
        float2 P;  P.x = fmaf(sca, v1x,  m1 * v1y);                           \
                   P.y = fmaf(sca, v1y, -m1 * v1x);                           \
        float2 Q;  Q.x = P.x - Bv.x;  Q.y = P.y - Bv.y;

    // ---- prime: P/Q of the initial state into buffer 1 (stale source @ s=0) ----
    {
        AB_MATH(posB0)
        PsB1[t] = P;
        QsB1[t] = Q;
        if (t == NA - 1) {
            float scb = k_str * (1.0f - ilb);
            PsB1[NA] = make_float2(scb * v2x, scb * v2y);
        }
    }
    __syncthreads();

    // one barrier per step; cross-seam P/Q (lanes 62,63) read 1-step-stale buffer
#define STEP(posR, posW, PsF, QsF, PsS, QsS)                                  \
    {                                                                         \
        AB_MATH(posR)                                                         \
        PsF[t] = P;                                                           \
        QsF[t] = Q;                                                           \
        if (t == NA - 1) {                                                    \
            float scb = k_str * (1.0f - ilb);                                 \
            PsF[NA] = make_float2(scb * v2x, scb * v2y);                      \
        }                                                                     \
        __asm__ __volatile__("" ::: "memory");  /* keep reads below writes */ \
        if (t < 1023) {                                                       \
            float2 Pn = (l >= 62 ? PsS : PsF)[t + 2];                         \
            float2 Qm = (l == 63 ? QsS : QsF)[t + 1];                         \
            float fx = Pn.x - Qm.x - Bv.x;                                    \
            float fy = Pn.y - Qm.y - Bv.y;                                    \
            vel.x += 0.001f * (fx - 2.0f * vel.x);                            \
            vel.y += 0.001f * (fy - 2.0f * vel.y);                            \
            myp.x += 0.001f * vel.x;                                          \
            myp.y += 0.001f * vel.y;                                          \
            posW[t + 2] = myp;                                                \
        }                                                                     \
        __syncthreads();                                                      \
    }

    for (int s2 = 0; s2 < 32; ++s2) {
        STEP(posB0, posB1, PsB0, QsB0, PsB1, QsB1)   // even step
        STEP(posB1, posB0, PsB1, QsB1, PsB0, QsB0)   // odd step
    }
#undef STEP
#undef AB_MATH

    // ---- epilogue ----
    float2* o = (float2*)(out + (size_t)b * 2052);
    o[t + 2] = myp;              // t=1023 writes node 1025 = tip
    if (t < 2) o[t] = posB0[t];
}

extern "C" void kernel_launch(void* const* d_in, const int* in_sizes, int n_in,
                              void* d_out, int out_size, void* d_ws, size_t ws_size,
                              hipStream_t stream) {
    const float* pos0   = (const float*)d_in[0];
    const float* tip    = (const float*)d_in[1];
    const float* thetas = (const float*)d_in[2];
    const int*   buckle = (const int*)  d_in[3];
    const float* ks     = (const float*)d_in[4];
    const float* ko     = (const float*)d_in[5];
    const float* kr     = (const float*)d_in[6];
    float* out = (float*)d_out;
    hipLaunchKernelGGL(equil_kernel, dim3(256), dim3(BLK), 0, stream,
                       pos0, tip, thetas, buckle, ks, ko, kr, out);
}